// Round 8
// baseline (107.414 us; speedup 1.0000x reference)
//
#include <hip/hip_runtime.h>
#include <math.h>

#define F_    16
#define NV_   4096
#define NT_   512
#define M_    4096
#define PPF_  (NV_ + NT_)        // 4608 points per frame
#define NPTS_ (F_ * PPF_)        // 73728 total points
#define SCALE_INV 10.0f          // 1 / 0.1

#define TPB    256
#define NPB    36                // point-blocks (2048 pts each)
#define NCHUNK 32                // model chunks (128 models each); grid 36x32 = 1152 blocks
#define CPM    128               // models per chunk
#define PPT    8                 // points per thread (4 f32 pairs)

#define PART_OFF (72 * 1024)     // ws layout: [0,1KB) poses, [1KB,65KB) feat, 72KB+ partials

typedef float v2f __attribute__((ext_vector_type(2)));

// ---------------------------------------------------------------- pose math
__device__ inline void rot_from_omega(float ox, float oy, float oz, float dt,
                                      float* R) {
    // R = I + sin(theta*dt)*S + (1-cos(theta*dt))*S^2,  S = skew(omega/max(theta,1e-8))
    float theta = sqrtf(ox * ox + oy * oy + oz * oz);
    float inv = 1.0f / fmaxf(theta, 1e-8f);
    float ax = ox * inv, ay = oy * inv, az = oz * inv;
    float s = sinf(theta * dt);
    float c = 1.0f - cosf(theta * dt);
    R[0] = 1.0f - c * (ay * ay + az * az);
    R[1] = -s * az + c * ax * ay;
    R[2] =  s * ay + c * ax * az;
    R[3] =  s * az + c * ax * ay;
    R[4] = 1.0f - c * (ax * ax + az * az);
    R[5] = -s * ax + c * ay * az;
    R[6] = -s * ay + c * ax * az;
    R[7] =  s * ax + c * ay * az;
    R[8] = 1.0f - c * (ax * ax + ay * ay);
}

// ---------------------------------------------------------------- packed distance core
// 2 models x 4 point-pairs; model quads live in SGPR PAIRS (s-constraints) so
// the inner loop has ZERO LDS / ZERO vector-memory traffic. op_sel encodings
// byte-identical to the r6/r7 numerically-proven ones. 24 pk_fma + 8 min3 here.
__device__ __forceinline__ void pkdist2(v2f qa01, v2f qa23, v2f qb01, v2f qb23,
                                        const v2f* c0, const v2f* c1,
                                        const v2f* c2, float* dm) {
    v2f A0, A1, A2, A3, B0, B1, B2, B3;
    asm(// z-stage: acc = fma(-2gz, z, w)
        "v_pk_fma_f32 %0, %9, %20, %9  op_sel:[0,0,1] op_sel_hi:[0,1,1]\n\t"
        "v_pk_fma_f32 %1, %9, %21, %9  op_sel:[0,0,1] op_sel_hi:[0,1,1]\n\t"
        "v_pk_fma_f32 %2, %9, %22, %9  op_sel:[0,0,1] op_sel_hi:[0,1,1]\n\t"
        "v_pk_fma_f32 %3, %9, %23, %9  op_sel:[0,0,1] op_sel_hi:[0,1,1]\n\t"
        "v_pk_fma_f32 %4, %11, %20, %11 op_sel:[0,0,1] op_sel_hi:[0,1,1]\n\t"
        "v_pk_fma_f32 %5, %11, %21, %11 op_sel:[0,0,1] op_sel_hi:[0,1,1]\n\t"
        "v_pk_fma_f32 %6, %11, %22, %11 op_sel:[0,0,1] op_sel_hi:[0,1,1]\n\t"
        "v_pk_fma_f32 %7, %11, %23, %11 op_sel:[0,0,1] op_sel_hi:[0,1,1]\n\t"
        // y-stage: acc += -2gy * y
        "v_pk_fma_f32 %0, %8, %16, %0  op_sel:[1,0,0] op_sel_hi:[1,1,1]\n\t"
        "v_pk_fma_f32 %1, %8, %17, %1  op_sel:[1,0,0] op_sel_hi:[1,1,1]\n\t"
        "v_pk_fma_f32 %2, %8, %18, %2  op_sel:[1,0,0] op_sel_hi:[1,1,1]\n\t"
        "v_pk_fma_f32 %3, %8, %19, %3  op_sel:[1,0,0] op_sel_hi:[1,1,1]\n\t"
        "v_pk_fma_f32 %4, %10, %16, %4 op_sel:[1,0,0] op_sel_hi:[1,1,1]\n\t"
        "v_pk_fma_f32 %5, %10, %17, %5 op_sel:[1,0,0] op_sel_hi:[1,1,1]\n\t"
        "v_pk_fma_f32 %6, %10, %18, %6 op_sel:[1,0,0] op_sel_hi:[1,1,1]\n\t"
        "v_pk_fma_f32 %7, %10, %19, %7 op_sel:[1,0,0] op_sel_hi:[1,1,1]\n\t"
        // x-stage: acc += -2gx * x
        "v_pk_fma_f32 %0, %8, %12, %0  op_sel:[0,0,0] op_sel_hi:[0,1,1]\n\t"
        "v_pk_fma_f32 %1, %8, %13, %1  op_sel:[0,0,0] op_sel_hi:[0,1,1]\n\t"
        "v_pk_fma_f32 %2, %8, %14, %2  op_sel:[0,0,0] op_sel_hi:[0,1,1]\n\t"
        "v_pk_fma_f32 %3, %8, %15, %3  op_sel:[0,0,0] op_sel_hi:[0,1,1]\n\t"
        "v_pk_fma_f32 %4, %10, %12, %4 op_sel:[0,0,0] op_sel_hi:[0,1,1]\n\t"
        "v_pk_fma_f32 %5, %10, %13, %5 op_sel:[0,0,0] op_sel_hi:[0,1,1]\n\t"
        "v_pk_fma_f32 %6, %10, %14, %6 op_sel:[0,0,0] op_sel_hi:[0,1,1]\n\t"
        "v_pk_fma_f32 %7, %10, %15, %7 op_sel:[0,0,0] op_sel_hi:[0,1,1]"
        : "=&v"(A0), "=&v"(A1), "=&v"(A2), "=&v"(A3),
          "=&v"(B0), "=&v"(B1), "=&v"(B2), "=&v"(B3)
        : "s"(qa01), "s"(qa23), "s"(qb01), "s"(qb23),
          "v"(c0[0]), "v"(c0[1]), "v"(c0[2]), "v"(c0[3]),
          "v"(c1[0]), "v"(c1[1]), "v"(c1[2]), "v"(c1[3]),
          "v"(c2[0]), "v"(c2[1]), "v"(c2[2]), "v"(c2[3]));
    dm[0] = fminf(fminf(A0.x, B0.x), dm[0]);
    dm[1] = fminf(fminf(A0.y, B0.y), dm[1]);
    dm[2] = fminf(fminf(A1.x, B1.x), dm[2]);
    dm[3] = fminf(fminf(A1.y, B1.y), dm[3]);
    dm[4] = fminf(fminf(A2.x, B2.x), dm[4]);
    dm[5] = fminf(fminf(A2.y, B2.y), dm[5]);
    dm[6] = fminf(fminf(A3.x, B3.x), dm[6]);
    dm[7] = fminf(fminf(A3.y, B3.y), dm[7]);
}

// ---------------------------------------------------------------- prep (ws is free: poison fill is unconditional)
__global__ void prep_kernel(const float* __restrict__ state,
                            const float* __restrict__ phys,
                            const float* __restrict__ dts,
                            const float* __restrict__ model,
                            float* __restrict__ ws_pose,
                            float4* __restrict__ ws_feat) {
    const int b = blockIdx.x, t = threadIdx.x;
    if (b == 0) {
        __shared__ float sRs[F_ * 9];
        __shared__ float sdt[F_ * 3];
        if (t < F_) {
            float ox, oy, oz, dt;
            if (t == 0) { ox = state[3]; oy = state[4]; oz = state[5]; dt = 1.0f; }
            else        { ox = phys[t * 12 + 9]; oy = phys[t * 12 + 10];
                          oz = phys[t * 12 + 11]; dt = dts[t]; }
            float Rs[9];
            rot_from_omega(ox, oy, oz, dt, Rs);
            for (int j = 0; j < 9; ++j) sRs[t * 9 + j] = Rs[j];
            if (t > 0) {
                sdt[t * 3 + 0] = phys[t * 12 + 6] * dt;
                sdt[t * 3 + 1] = phys[t * 12 + 7] * dt;
                sdt[t * 3 + 2] = phys[t * 12 + 8] * dt;
            }
        }
        if (t == 0) {   // same wave as writers -> lockstep-ordered
            float R[9];
            for (int j = 0; j < 9; ++j) R[j] = sRs[j];
            float tr[3] = {state[0], state[1], state[2]};
            for (int i = 0; i < F_; ++i) {
                if (i > 0) {
                    tr[0] += sdt[i * 3 + 0];
                    tr[1] += sdt[i * 3 + 1];
                    tr[2] += sdt[i * 3 + 2];
                    float Rn[9];
                    const float* Rsp = sRs + i * 9;
                    for (int r = 0; r < 3; ++r)
                        for (int c2 = 0; c2 < 3; ++c2)
                            Rn[r * 3 + c2] = Rsp[r * 3 + 0] * R[0 + c2] +
                                             Rsp[r * 3 + 1] * R[3 + c2] +
                                             Rsp[r * 3 + 2] * R[6 + c2];
                    for (int j = 0; j < 9; ++j) R[j] = Rn[j];
                }
                float* o = ws_pose + i * 12;
                o[0] = tr[0]; o[1] = tr[1]; o[2] = tr[2];
                for (int j = 0; j < 9; ++j) o[3 + j] = R[j] * SCALE_INV;
            }
        }
    } else {
        const int id = (b - 1) * 256 + t;   // 0..4095, linear (chunk = id>>7)
        float gx = model[id * 3 + 0], gy = model[id * 3 + 1], gz = model[id * 3 + 2];
        ws_feat[id] = make_float4(-2.0f * gx, -2.0f * gy, -2.0f * gz,
                                  gx * gx + gy * gy + gz * gz);
    }
}

// ---------------------------------------------------------------- main kernel
// r2-r7 post-mortem: wall pinned at 45-48us across 2x VALU / 2x LDS variations
// -> LDS-staged inner loop is the shared suspect. This version's inner loop
// issues ZERO ds ops and ZERO vector-memory ops: model features stream through
// the scalar pipe (s_load -> SGPR pairs, "s" asm constraints), points live in
// VGPRs. grid (36 pt-blocks x 32 chunks); partials to ws; reduce kernel sums.
__global__ __launch_bounds__(TPB, 4) void chamfer_main(
    const float* __restrict__ vis, const float* __restrict__ tac,
    const float* __restrict__ ws_pose, const float4* __restrict__ ws_feat,
    float* __restrict__ partials) {
    __shared__ float spose[F_ * 12];
    const int t  = threadIdx.x;
    const int pb = blockIdx.x;              // 0..35
    const int ch = blockIdx.y;              // 0..31

    if (t < F_ * 12) spose[t] = ws_pose[t];
    __syncthreads();

    // ---- transform my 8 points (lane-interleaved: pt = pb*2048 + k*256 + t) ----
    v2f c0p[4], c1p[4], c2p[4];
    float cn[PPT], dm[PPT];
#pragma unroll
    for (int k = 0; k < PPT; ++k) {
        int pt  = pb * 2048 + k * 256 + t;
        int f   = pt / PPF_;                // per-point (blocks straddle frames)
        int loc = pt - f * PPF_;
        const float* p = (loc < NV_) ? (vis + ((size_t)f * NV_ + loc) * 3)
                                     : (tac + ((size_t)f * NT_ + (loc - NV_)) * 3);
        const float* ps = spose + f * 12;
        float d0 = p[0] - ps[0], d1 = p[1] - ps[1], d2 = p[2] - ps[2];
        const float* R = ps + 3;
        float x = d0 * R[0] + d1 * R[3] + d2 * R[6];
        float y = d0 * R[1] + d1 * R[4] + d2 * R[7];
        float z = d0 * R[2] + d1 * R[5] + d2 * R[8];
        cn[k] = x * x + y * y + z * z;
        dm[k] = 3.4e38f;
        if (k & 1) { c0p[k >> 1].y = x; c1p[k >> 1].y = y; c2p[k >> 1].y = z; }
        else       { c0p[k >> 1].x = x; c1p[k >> 1].x = y; c2p[k >> 1].x = z; }
    }

    // ---- inner loop: 128 models via SGPR scalar loads; pure VALU + SMEM ----
    const v2f* fch = (const v2f*)(ws_feat + (size_t)ch * CPM);  // uniform addr
#pragma unroll 4
    for (int m = 0; m < CPM; m += 2) {
        v2f qa01 = fch[2 * m + 0];          // {-2gx,-2gy}  -> s_load_dwordx2
        v2f qa23 = fch[2 * m + 1];          // {-2gz,  w}
        v2f qb01 = fch[2 * m + 2];
        v2f qb23 = fch[2 * m + 3];
        pkdist2(qa01, qa23, qb01, qb23, c0p, c1p, c2p, dm);
    }

    // ---- coalesced partial store ----
#pragma unroll
    for (int k = 0; k < PPT; ++k)
        partials[(size_t)ch * NPTS_ + pb * 2048 + k * 256 + t] = dm[k] + cn[k];
}

// ---------------------------------------------------------------- reduce (r0-proven structure)
__global__ __launch_bounds__(TPB) void chamfer_reduce(
    const float* __restrict__ partials, float* __restrict__ out) {
    __shared__ float sw[TPB / 64];
    const int pt = blockIdx.x * TPB + threadIdx.x;   // grid 288
    float m = partials[pt];
    for (int ch = 1; ch < NCHUNK; ++ch)
        m = fminf(m, partials[(size_t)ch * NPTS_ + pt]);
    const int loc = pt % PPF_;
    const float w = (loc < NV_) ? (1.0f / NV_) : (0.1f / NT_);
    float v = m * w;
#pragma unroll
    for (int off = 32; off > 0; off >>= 1) v += __shfl_down(v, off);
    if ((threadIdx.x & 63) == 0) sw[threadIdx.x >> 6] = v;
    __syncthreads();
    if (threadIdx.x == 0) {
        float s = 0.0f;
        for (int i = 0; i < TPB / 64; ++i) s += sw[i];
        atomicAdd(out, s);
    }
}

// ---------------------------------------------------------------- safety fallback (ws too small; never per evidence)
__global__ __launch_bounds__(TPB) void chamfer_fb(
    const float* __restrict__ state, const float* __restrict__ model,
    const float* __restrict__ vis, const float* __restrict__ tac,
    const float* __restrict__ phys, const float* __restrict__ dts,
    float* __restrict__ out) {
    __shared__ float sw[4];
    const int pt = blockIdx.x * TPB + threadIdx.x;
    const int f = pt / PPF_, loc = pt - f * PPF_;
    float R[9], tr[3] = {state[0], state[1], state[2]};
    rot_from_omega(state[3], state[4], state[5], 1.0f, R);
    for (int i = 1; i <= f; ++i) {
        float dt = dts[i];
        tr[0] += phys[i * 12 + 6] * dt;
        tr[1] += phys[i * 12 + 7] * dt;
        tr[2] += phys[i * 12 + 8] * dt;
        float Rs[9], Rn[9];
        rot_from_omega(phys[i * 12 + 9], phys[i * 12 + 10], phys[i * 12 + 11], dt, Rs);
        for (int r = 0; r < 3; ++r)
            for (int c2 = 0; c2 < 3; ++c2)
                Rn[r * 3 + c2] = Rs[r * 3 + 0] * R[0 + c2] +
                                 Rs[r * 3 + 1] * R[3 + c2] +
                                 Rs[r * 3 + 2] * R[6 + c2];
        for (int j = 0; j < 9; ++j) R[j] = Rn[j];
    }
    for (int j = 0; j < 9; ++j) R[j] *= SCALE_INV;
    const float* p = (loc < NV_) ? (vis + ((size_t)f * NV_ + loc) * 3)
                                 : (tac + ((size_t)f * NT_ + (loc - NV_)) * 3);
    float d0 = p[0] - tr[0], d1 = p[1] - tr[1], d2 = p[2] - tr[2];
    float x = d0 * R[0] + d1 * R[3] + d2 * R[6];
    float y = d0 * R[1] + d1 * R[4] + d2 * R[7];
    float z = d0 * R[2] + d1 * R[5] + d2 * R[8];
    float cn = x * x + y * y + z * z;
    float mn = 3.4e38f;
    for (int i = 0; i < M_; ++i) {
        float gx = model[i * 3], gy = model[i * 3 + 1], gz = model[i * 3 + 2];
        float gn = gx * gx + gy * gy + gz * gz;
        float dd = fmaf(-2.0f * gx, x, fmaf(-2.0f * gy, y, fmaf(-2.0f * gz, z, gn)));
        mn = fminf(mn, dd);
    }
    float w = (loc < NV_) ? (1.0f / NV_) : (0.1f / NT_);
    float v = (mn + cn) * w;
    for (int off = 32; off > 0; off >>= 1) v += __shfl_down(v, off);
    if ((threadIdx.x & 63) == 0) sw[threadIdx.x >> 6] = v;
    __syncthreads();
    if (threadIdx.x == 0) atomicAdd(out, sw[0] + sw[1] + sw[2] + sw[3]);
}

// ---------------------------------------------------------------- launch
extern "C" void kernel_launch(void* const* d_in, const int* in_sizes, int n_in,
                              void* d_out, int out_size, void* d_ws, size_t ws_size,
                              hipStream_t stream) {
    const float* state = (const float*)d_in[0];   // (6,)
    const float* model = (const float*)d_in[1];   // (M,3)
    const float* vis   = (const float*)d_in[2];   // (F,NV,3)
    const float* tac   = (const float*)d_in[3];   // (F,NT,3)
    const float* phys  = (const float*)d_in[4];   // (F,12)
    const float* dts   = (const float*)d_in[5];   // (F,)
    float* out = (float*)d_out;

    const size_t NEED = PART_OFF + (size_t)NCHUNK * NPTS_ * sizeof(float);  // ~9.5MB
    hipMemsetAsync(out, 0, sizeof(float), stream);
    if (ws_size >= NEED) {
        float*  ws_pose  = (float*)d_ws;
        float4* ws_feat  = (float4*)((char*)d_ws + 1024);
        float*  partials = (float*)((char*)d_ws + PART_OFF);
        prep_kernel<<<17, 256, 0, stream>>>(state, phys, dts, model, ws_pose, ws_feat);
        dim3 grid(NPB, NCHUNK);
        chamfer_main<<<grid, TPB, 0, stream>>>(vis, tac, ws_pose, ws_feat, partials);
        chamfer_reduce<<<NPTS_ / TPB, TPB, 0, stream>>>(partials, out);
    } else {
        chamfer_fb<<<NPTS_ / TPB, TPB, 0, stream>>>(state, model, vis, tac, phys,
                                                    dts, out);
    }
}